// Round 5
// baseline (155.495 us; speedup 1.0000x reference)
//
#include <hip/hip_runtime.h>

#define BB 32768
#define BS (BB*16)   // 524288

typedef __attribute__((ext_vector_type(8))) short bf8v;   // 8 bf16 (4 VGPRs)
typedef __attribute__((ext_vector_type(4))) float f4v;

// ---- ws float offsets ----
#define RECO 64
#define TAB  128             // disc F table, 2049 floats over [-8,8], step 1/128
#define NTAB 2049
#define HFO  8448
#define HBO  (HFO+BS)

// ---- table-path LDS layout (USHORT indices; weights stored bf16) ----
#define PW0 0
#define PB0 96
#define PW1 192    // 48 rows x 36
#define PB1 1920
#define PW2 1968   // 24 x 20
#define PB2 2448
#define PW3 2472   // 48 x 12
#define PB3 3048
#define PW4 3096   // 96 x 20
#define PB4 5016
#define POW 5112
#define POB 5144
#define PNU 5148             // ushorts = 10.3KB

#define SMF 2580             // floats: 10320 B >= table's 10296 B; scan uses 0

#define NSCAN 512            // scan blocks; each wave runs 2 independent chains
#define NTABB 129
// blocks 0..511 = scan (2 tiles/wave), 512..640 = table, 641 = decoder

__device__ __forceinline__ float sigm(float x){
    return __builtin_amdgcn_rcpf(1.f + __expf(-x));
}
__device__ __forceinline__ float tanh_f(float x){
    return 1.f - 2.f * __builtin_amdgcn_rcpf(1.f + __expf(2.f * x));
}
__device__ __forceinline__ float dunit(float gi, float gg, float go){
    return sigm(go) * tanh_f(sigm(gi) * tanh_f(gg));
}
__device__ __forceinline__ unsigned short f2bf(float f){   // RNE
    union { float f; unsigned int i; } v; v.f = f;
    unsigned int x = v.i;
    unsigned int r = x + 0x7fffu + ((x >> 16) & 1u);
    return (unsigned short)(r >> 16);
}
__device__ __forceinline__ float bfu(unsigned short s){
    union { unsigned u; float f; } v; v.u = ((unsigned)s) << 16; return v.f;
}
__device__ __forceinline__ float bflo(unsigned p){
    union { unsigned u; float f; } v; v.u = p << 16; return v.f;
}
__device__ __forceinline__ float bfhi(unsigned p){
    union { unsigned u; float f; } v; v.u = p & 0xffff0000u; return v.f;
}

struct P29 { const float* p[29]; };
// 0 values 1 masks 2-4 g_fwd(Wih,Whh,b) 5-7 g_bwd 8 impW 9 impb
// 10 fcW 11 fcb 12-14 dec(Wih,Whh,b) 15 dec_out_W 16 dec_out_b 17 disc_out_W
// 18 disc_out_b 19/20 d_W_0/d_b_0 ... 27/28 d_W_4/d_b_4

// A fragment (R1-validated): W[row][k] at lane: row=lane&15, k=quad*8+j.
// quads 0,1 = Whh row; quad 2, j=0 (k=16) = Wih column (cc enters via the
// B-side patch at the same k-slot).
__device__ __forceinline__ bf8v makeB(const float* Whh, const float* Wih,
                                      int row, int quad)
{
    bf8v B = {0,0,0,0,0,0,0,0};
    if (quad < 2) {
        const float4* p = (const float4*)(Whh + row*16 + quad*8);
        float4 a0 = p[0], a1 = p[1];
        B[0]=(short)f2bf(a0.x); B[1]=(short)f2bf(a0.y);
        B[2]=(short)f2bf(a0.z); B[3]=(short)f2bf(a0.w);
        B[4]=(short)f2bf(a1.x); B[5]=(short)f2bf(a1.y);
        B[6]=(short)f2bf(a1.z); B[7]=(short)f2bf(a1.w);
    } else if (quad == 2) {
        B[0] = (short)f2bf(Wih[row]);
    }
    return B;
}

// ==== k_main: 0..511 MFMA scan | 512..640 disc F table | 641 decoder ====
// launch_bounds(256,4): cap VGPR at 128 -> 4 waves/SIMD -> 8 chains/SIMD.
__global__ __launch_bounds__(256, 4)
void k_main(P29 a, const int* __restrict__ masks, float* __restrict__ ws)
{
    __shared__ __align__(16) float smem[SMF];
    int tid = threadIdx.x;

    if (blockIdx.x < NSCAN) {
        // ------- scan path: R1 dataflow x 2 independent chains per wave -------
        int lane = tid & 63;
        int wv   = tid >> 6;
        int m    = lane & 15;        // batch column within tile
        int quad = lane >> 4;
        int dir  = (int)(blockIdx.x >= 256);
        int b0   = (blockIdx.x & 255) * 128 + wv * 32;   // 2 tiles: b0, b0+16

        const float* __restrict__ Wih = a.p[2 + 3*dir];
        const float* __restrict__ Whh = a.p[3 + 3*dir];
        const float* __restrict__ bia = a.p[4 + 3*dir];

        // A operands (shared by both chains)
        bf8v Ai = makeB(Whh, Wih, m,      quad);
        bf8v Af = makeB(Whh, Wih, 16+m,   quad);
        bf8v Ag = makeB(Whh, Wih, 32+m,   quad);
        bf8v Ao = makeB(Whh, Wih, 48+m,   quad);
        bf8v Ap = {0,0,0,0,0,0,0,0};
        if (quad < 2) {
            const float4* p = (const float4*)(a.p[8] + quad*8);
            float4 a0 = p[0], a1 = p[1];
            Ap[0]=(short)f2bf(a0.x); Ap[1]=(short)f2bf(a0.y);
            Ap[2]=(short)f2bf(a0.z); Ap[3]=(short)f2bf(a0.w);
            Ap[4]=(short)f2bf(a1.x); Ap[5]=(short)f2bf(a1.y);
            Ap[6]=(short)f2bf(a1.z); Ap[7]=(short)f2bf(a1.w);
        }
        float impb = a.p[9][0];
        const f4v cz = {0.f, 0.f, 0.f, 0.f};   // zero C for dimp; impb added in select

        // Gate biases as the MFMA C operand: C[u][m] = b[u], u = quad*4+r
        f4v cbi, cbf, cbg, cbo;
        {
            float4 t;
            t = *(const float4*)(bia +      quad*4); cbi = (f4v){t.x,t.y,t.z,t.w};
            t = *(const float4*)(bia + 16 + quad*4); cbf = (f4v){t.x,t.y,t.z,t.w};
            t = *(const float4*)(bia + 32 + quad*4); cbg = (f4v){t.x,t.y,t.z,t.w};
            t = *(const float4*)(bia + 48 + quad*4); cbo = (f4v){t.x,t.y,t.z,t.w};
        }

        // init cell: x = +-128, h=c=0 -> identical for both chains
        float sgn = dir ? -128.f : 128.f;
        float c[2][4], hl[2][4];
        {
            float4 wI = *(const float4*)(Wih +      quad*4);
            float4 wG = *(const float4*)(Wih + 32 + quad*4);
            float4 wO = *(const float4*)(Wih + 48 + quad*4);
            float wIv[4] = {wI.x, wI.y, wI.z, wI.w};
            float wGv[4] = {wG.x, wG.y, wG.z, wG.w};
            float wOv[4] = {wO.x, wO.y, wO.z, wO.w};
            #pragma unroll
            for (int r = 0; r < 4; r++) {
                float gi0 = sgn*wIv[r] + cbi[r];
                float gg0 = sgn*wGv[r] + cbg[r];
                float go0 = sgn*wOv[r] + cbo[r];
                float c0 = sigm(gi0) * tanh_f(gg0);
                float h0 = sigm(go0) * tanh_f(c0);
                c[0][r] = c0; c[1][r] = c0;
                hl[0][r] = h0; hl[1][r] = h0;
            }
        }
        unsigned u01[2], u23[2];
        #pragma unroll
        for (int s = 0; s < 2; s++) {
            asm("v_cvt_pk_bf16_f32 %0, %1, %2" : "=v"(u01[s]) : "v"(hl[s][0]), "v"(hl[s][1]));
            asm("v_cvt_pk_bf16_f32 %0, %1, %2" : "=v"(u23[s]) : "v"(hl[s][2]), "v"(hl[s][3]));
        }

        // bpermute sources: B word w needs h rows quad*8+2w,+1 -> lanes m+32q, m+32q+16
        int pa0 = ((m + quad*32)      & 63) << 2;
        int pa1 = ((m + quad*32 + 16) & 63) << 2;

        const float* xrow0 = a.p[0] + (size_t)(b0 + m) * 16;
        const int*   mrow0 = masks  + (size_t)(b0 + m) * 16;
        const float* xrow1 = xrow0 + 16*16;
        const int*   mrow1 = mrow0 + 16*16;

        #pragma unroll
        for (int t4 = 0; t4 < 4; t4++) {
            float4 xv0 = *(const float4*)(xrow0 + t4*4);
            int4   mv0 = *(const int4*)(mrow0 + t4*4);
            float4 xv1 = *(const float4*)(xrow1 + t4*4);
            int4   mv1 = *(const int4*)(mrow1 + t4*4);
            float xa[2][4] = {{xv0.x, xv0.y, xv0.z, xv0.w},
                              {xv1.x, xv1.y, xv1.z, xv1.w}};
            int   ma[2][4] = {{mv0.x, mv0.y, mv0.z, mv0.w},
                              {mv1.x, mv1.y, mv1.z, mv1.w}};
            #pragma unroll
            for (int j = 0; j < 4; j++) {
                union U4 { int i[4]; bf8v v; } B[2];
                #pragma unroll
                for (int s = 0; s < 2; s++) {
                    int w0 = __builtin_amdgcn_ds_bpermute(pa0, (int)u01[s]);
                    int w1 = __builtin_amdgcn_ds_bpermute(pa0, (int)u23[s]);
                    int w2 = __builtin_amdgcn_ds_bpermute(pa1, (int)u01[s]);
                    int w3 = __builtin_amdgcn_ds_bpermute(pa1, (int)u23[s]);
                    bool hi2 = quad >= 2;
                    B[s].i[0] = hi2 ? 0 : w0;
                    B[s].i[1] = hi2 ? 0 : w1;
                    B[s].i[2] = hi2 ? 0 : w2;
                    B[s].i[3] = hi2 ? 0 : w3;
                }
                #pragma unroll
                for (int s = 0; s < 2; s++) {
                    f4v dimp = __builtin_amdgcn_mfma_f32_16x16x32_bf16(Ap, B[s].v, cz, 0, 0, 0);
                    float cc = ma[s][j] ? (dimp[0] + impb) : xa[s][j];
                    unsigned ccw;
                    asm("v_cvt_pk_bf16_f32 %0, %1, %2" : "=v"(ccw) : "v"(cc), "v"(0.f));
                    if (quad == 2) B[s].i[0] = (int)ccw;   // cc at k=16
                    f4v di  = __builtin_amdgcn_mfma_f32_16x16x32_bf16(Ai, B[s].v, cbi, 0, 0, 0);
                    f4v df_ = __builtin_amdgcn_mfma_f32_16x16x32_bf16(Af, B[s].v, cbf, 0, 0, 0);
                    f4v dg  = __builtin_amdgcn_mfma_f32_16x16x32_bf16(Ag, B[s].v, cbg, 0, 0, 0);
                    f4v dO  = __builtin_amdgcn_mfma_f32_16x16x32_bf16(Ao, B[s].v, cbo, 0, 0, 0);
                    #pragma unroll
                    for (int r = 0; r < 4; r++) {
                        float cn = sigm(df_[r])*c[s][r] + sigm(di[r])*tanh_f(dg[r]);
                        c[s][r] = cn;
                        hl[s][r] = sigm(dO[r])*tanh_f(cn);
                    }
                    asm("v_cvt_pk_bf16_f32 %0, %1, %2" : "=v"(u01[s]) : "v"(hl[s][0]), "v"(hl[s][1]));
                    asm("v_cvt_pk_bf16_f32 %0, %1, %2" : "=v"(u23[s]) : "v"(hl[s][2]), "v"(hl[s][3]));
                }
            }
        }
        // final h: lane holds h[u=quad*4+r][m] -> ws[... + m*16 + u]
        float* outp = ws + HFO + (size_t)dir*BS + (size_t)b0*16;
        #pragma unroll
        for (int r = 0; r < 4; r++) {
            outp[m*16 + quad*4 + r]        = hl[0][r];
            outp[(16 + m)*16 + quad*4 + r] = hl[1][r];
        }
        return;
    }

    if (blockIdx.x < NSCAN + NTABB) {
        // -------- F-table path: bf16 weights in LDS (10.3KB), 16 lanes/entry --------
        unsigned short* wl = (unsigned short*)smem;
#define STAGE(WS, BSi, h, K, padK, wdst, bdst) \
    { const float* Wp = a.p[WS]; const float* Bp2 = a.p[BSi]; \
      for (int i = tid; i < 3*(h)*(K); i += 256){ \
        int r = i/(K), k = i - r*(K); int g = r/(h), u0 = r - g*(h); \
        int sr = (g==0? u0 : (g==1? 2*(h)+u0 : 3*(h)+u0)); \
        wl[(wdst) + r*(padK) + k] = f2bf(Wp[sr*(K) + k]); } \
      for (int i = tid; i < 3*(h); i += 256){ \
        int g = i/(h), u0 = i - g*(h); \
        int sr = (g==0? u0 : (g==1? 2*(h)+u0 : 3*(h)+u0)); \
        wl[(bdst) + i] = f2bf(Bp2[sr]); } }
        STAGE(19, 20, 32,  1,  1, PW0, PB0)
        STAGE(21, 22, 16, 32, 36, PW1, PB1)
        STAGE(23, 24,  8, 16, 20, PW2, PB2)
        STAGE(25, 26, 16,  8, 12, PW3, PB3)
        STAGE(27, 28, 32, 16, 20, PW4, PB4)
#undef STAGE
        { const float* s = a.p[17]; for (int i = tid; i < 32; i += 256) wl[POW+i] = f2bf(s[i]); }
        if (tid == 0) wl[POB] = f2bf(a.p[18][0]);
        __syncthreads();
        int u = tid & 15;
        int gbase = (tid & 63) & 48;
        int gid = (blockIdx.x - NSCAN) * 16 + (tid >> 4);
        const uint2* w2 = (const uint2*)wl;      // index = ushort_idx/4
        float xin = -8.f + (float)gid * (1.f/128.f);
        float lo = dunit(xin*bfu(wl[PW0+u])    + bfu(wl[PB0+u]),
                         xin*bfu(wl[PW0+32+u]) + bfu(wl[PB0+32+u]),
                         xin*bfu(wl[PW0+64+u]) + bfu(wl[PB0+64+u]));
        float hi = dunit(xin*bfu(wl[PW0+16+u]) + bfu(wl[PB0+16+u]),
                         xin*bfu(wl[PW0+48+u]) + bfu(wl[PB0+48+u]),
                         xin*bfu(wl[PW0+80+u]) + bfu(wl[PB0+80+u]));
        float A0[32];
        #pragma unroll
        for (int k = 0; k < 16; k++) { A0[k] = __shfl(lo, gbase+k); A0[16+k] = __shfl(hi, gbase+k); }
        float gi = bfu(wl[PB1+u]), gg = bfu(wl[PB1+16+u]), go = bfu(wl[PB1+32+u]);
        int bi_ = (PW1 + u*36)>>2, bg_ = (PW1 + (16+u)*36)>>2, bo_ = (PW1 + (32+u)*36)>>2;
        #pragma unroll
        for (int q = 0; q < 8; q++) {
            uint2 wi = w2[bi_+q], wg = w2[bg_+q], wo = w2[bo_+q];
            float b0=A0[4*q], b1=A0[4*q+1], b2=A0[4*q+2], b3=A0[4*q+3];
            gi += b0*bflo(wi.x) + b1*bfhi(wi.x) + b2*bflo(wi.y) + b3*bfhi(wi.y);
            gg += b0*bflo(wg.x) + b1*bfhi(wg.x) + b2*bflo(wg.y) + b3*bfhi(wg.y);
            go += b0*bflo(wo.x) + b1*bfhi(wo.x) + b2*bflo(wo.y) + b3*bfhi(wo.y);
        }
        float a1 = dunit(gi, gg, go);
        float A1[16];
        #pragma unroll
        for (int k = 0; k < 16; k++) A1[k] = __shfl(a1, gbase+k);
        int v = u & 7;
        gi = bfu(wl[PB2+v]); gg = bfu(wl[PB2+8+v]); go = bfu(wl[PB2+16+v]);
        bi_ = (PW2 + v*20)>>2; bg_ = (PW2 + (8+v)*20)>>2; bo_ = (PW2 + (16+v)*20)>>2;
        #pragma unroll
        for (int q = 0; q < 4; q++) {
            uint2 wi = w2[bi_+q], wg = w2[bg_+q], wo = w2[bo_+q];
            float b0=A1[4*q], b1=A1[4*q+1], b2=A1[4*q+2], b3=A1[4*q+3];
            gi += b0*bflo(wi.x) + b1*bfhi(wi.x) + b2*bflo(wi.y) + b3*bfhi(wi.y);
            gg += b0*bflo(wg.x) + b1*bfhi(wg.x) + b2*bflo(wg.y) + b3*bfhi(wg.y);
            go += b0*bflo(wo.x) + b1*bfhi(wo.x) + b2*bflo(wo.y) + b3*bfhi(wo.y);
        }
        float a2 = dunit(gi, gg, go);
        float A2[8];
        #pragma unroll
        for (int k = 0; k < 8; k++) A2[k] = __shfl(a2, gbase+k);
        gi = bfu(wl[PB3+u]); gg = bfu(wl[PB3+16+u]); go = bfu(wl[PB3+32+u]);
        bi_ = (PW3 + u*12)>>2; bg_ = (PW3 + (16+u)*12)>>2; bo_ = (PW3 + (32+u)*12)>>2;
        #pragma unroll
        for (int q = 0; q < 2; q++) {
            uint2 wi = w2[bi_+q], wg = w2[bg_+q], wo = w2[bo_+q];
            float b0=A2[4*q], b1=A2[4*q+1], b2=A2[4*q+2], b3=A2[4*q+3];
            gi += b0*bflo(wi.x) + b1*bfhi(wi.x) + b2*bflo(wi.y) + b3*bfhi(wi.y);
            gg += b0*bflo(wg.x) + b1*bfhi(wg.x) + b2*bflo(wg.y) + b3*bfhi(wg.y);
            go += b0*bflo(wo.x) + b1*bfhi(wo.x) + b2*bflo(wo.y) + b3*bfhi(wo.y);
        }
        float a3 = dunit(gi, gg, go);
        float A3[16];
        #pragma unroll
        for (int k = 0; k < 16; k++) A3[k] = __shfl(a3, gbase+k);
        float part;
        {
            float g0i = bfu(wl[PB4+u]),    g0g = bfu(wl[PB4+32+u]), g0o = bfu(wl[PB4+64+u]);
            float g1i = bfu(wl[PB4+16+u]), g1g = bfu(wl[PB4+48+u]), g1o = bfu(wl[PB4+80+u]);
            int c0i = (PW4 + u*20)>>2,      c0g = (PW4 + (32+u)*20)>>2, c0o = (PW4 + (64+u)*20)>>2;
            int c1i = (PW4 + (16+u)*20)>>2, c1g = (PW4 + (48+u)*20)>>2, c1o = (PW4 + (80+u)*20)>>2;
            #pragma unroll
            for (int q = 0; q < 4; q++) {
                float b0=A3[4*q], b1=A3[4*q+1], b2=A3[4*q+2], b3=A3[4*q+3];
                uint2 wi = w2[c0i+q], wg = w2[c0g+q], wo = w2[c0o+q];
                g0i += b0*bflo(wi.x) + b1*bfhi(wi.x) + b2*bflo(wi.y) + b3*bfhi(wi.y);
                g0g += b0*bflo(wg.x) + b1*bfhi(wg.x) + b2*bflo(wg.y) + b3*bfhi(wg.y);
                g0o += b0*bflo(wo.x) + b1*bfhi(wo.x) + b2*bflo(wo.y) + b3*bfhi(wo.y);
                wi = w2[c1i+q]; wg = w2[c1g+q]; wo = w2[c1o+q];
                g1i += b0*bflo(wi.x) + b1*bfhi(wi.x) + b2*bflo(wi.y) + b3*bfhi(wi.y);
                g1g += b0*bflo(wg.x) + b1*bfhi(wg.x) + b2*bflo(wg.y) + b3*bfhi(wg.y);
                g1o += b0*bflo(wo.x) + b1*bfhi(wo.x) + b2*bflo(wo.y) + b3*bfhi(wo.y);
            }
            part = dunit(g0i, g0g, g0o)*bfu(wl[POW+u]) + dunit(g1i, g1g, g1o)*bfu(wl[POW+16+u]);
        }
        part += __shfl_xor(part, 1);
        part += __shfl_xor(part, 2);
        part += __shfl_xor(part, 4);
        part += __shfl_xor(part, 8);
        if (u == 0 && gid < NTAB) ws[TAB + gid] = part + bfu(wl[POB]);
        return;
    }

    // ---------------- decoder block (batch-invariant scan) ----------------
    {
        float* dh = smem;
        float* dc = smem + 16;
        const float* Wih = a.p[12];
        const float* Whh = a.p[13];
        const float* bb  = a.p[14];
        const float* oW  = a.p[15];
        const float* ob  = a.p[16];
        float wii[16], wff[16], wgg[16], woo[16];
        float vii[16], vff[16], vgg[16], voo[16];
        float bi_r=0, bf_r=0, bg_r=0, bo_r=0;
        if (tid < 16) {
            int uu = tid;
            #pragma unroll
            for (int k = 0; k < 16; k++) {
                wii[k]=Wih[uu*16+k];      vii[k]=Whh[uu*16+k];
                wff[k]=Wih[(16+uu)*16+k]; vff[k]=Whh[(16+uu)*16+k];
                wgg[k]=Wih[(32+uu)*16+k]; vgg[k]=Whh[(32+uu)*16+k];
                woo[k]=Wih[(48+uu)*16+k]; voo[k]=Whh[(48+uu)*16+k];
            }
            bi_r=bb[uu]; bf_r=bb[16+uu]; bg_r=bb[32+uu]; bo_r=bb[48+uu];
            float gi = bi_r, gg = bg_r, go = bo_r;
            #pragma unroll
            for (int k = 0; k < 16; k++) {
                gi += 128.f * wii[k];
                gg += 128.f * wgg[k];
                go += 128.f * woo[k];
            }
            float cd0 = sigm(gi) * tanh_f(gg);
            dc[tid] = cd0; dh[tid] = sigm(go) * tanh_f(cd0);
        }
        __syncthreads();
        for (int t = 0; t < 16; t++) {
            float rx[16], rh[16], cold = 0.f;
            if (tid < 16) {
                #pragma unroll
                for (int k = 0; k < 16; k++) { rx[k] = dc[k]; rh[k] = dh[k]; }
                cold = dc[tid];
            }
            __syncthreads();
            if (tid < 16) {
                float gi = bi_r, gf = bf_r, gg = bg_r, go = bo_r;
                #pragma unroll
                for (int k = 0; k < 16; k++) {
                    gi += rx[k]*wii[k] + rh[k]*vii[k];
                    gf += rx[k]*wff[k] + rh[k]*vff[k];
                    gg += rx[k]*wgg[k] + rh[k]*vgg[k];
                    go += rx[k]*woo[k] + rh[k]*voo[k];
                }
                float cn = sigm(gf)*cold + sigm(gi)*tanh_f(gg);
                dc[tid] = cn; dh[tid] = sigm(go)*tanh_f(cn);
            }
            __syncthreads();
            if (tid == 0) {
                float o = ob[0];
                #pragma unroll
                for (int k = 0; k < 16; k++) o += dh[k] * oW[k];
                ws[RECO + t] = o;
            }
            __syncthreads();
        }
    }
}

// ---- k_post: 4 elements per thread; fcW/rec/table staged in LDS ----
__global__ __launch_bounds__(256) void k_post(P29 a, const int* __restrict__ masks,
                                              const float* __restrict__ ws,
                                              float* __restrict__ out)
{
    __shared__ float tab[NTAB];
    __shared__ __align__(16) float fw[256];
    __shared__ __align__(16) float rec[16];
    __shared__ float fb[16];
    int tid = threadIdx.x;
    for (int i = tid; i < NTAB; i += 256) tab[i] = ws[TAB + i];
    fw[tid] = a.p[10][tid];
    if (tid < 16) { fb[tid] = a.p[11][tid]; rec[tid] = ws[RECO + tid]; }
    __syncthreads();
    int T = blockIdx.x * 256 + tid;
    int b = T >> 2;
    int q = T & 3;
    int tq = q * 4;
    const float4* hf4 = (const float4*)(ws + HFO + (size_t)b*16);
    const float4* hb4 = (const float4*)(ws + HBO + (size_t)b*16);
    float4 s0, s1, s2, s3;
    {
        float4 f0=hf4[0], f1=hf4[1], f2=hf4[2], f3=hf4[3];
        float4 g0=hb4[0], g1=hb4[1], g2=hb4[2], g3=hb4[3];
        s0 = make_float4(f0.x+g0.x, f0.y+g0.y, f0.z+g0.z, f0.w+g0.w);
        s1 = make_float4(f1.x+g1.x, f1.y+g1.y, f1.z+g1.z, f1.w+g1.w);
        s2 = make_float4(f2.x+g2.x, f2.y+g2.y, f2.z+g2.z, f2.w+g2.w);
        s3 = make_float4(f3.x+g3.x, f3.y+g3.y, f3.z+g3.z, f3.w+g3.w);
    }
    float4 hq = (q==0) ? s0 : (q==1) ? s1 : (q==2) ? s2 : s3;
    float4 xv = *(const float4*)(a.p[0] + (size_t)b*16 + tq);
    int4   mv = *(const int4*)(masks + (size_t)b*16 + tq);
    float impv[4];
    impv[0] = mv.x ? xv.x : hq.x;
    impv[1] = mv.y ? xv.y : hq.y;
    impv[2] = mv.z ? xv.z : hq.z;
    impv[3] = mv.w ? xv.w : hq.w;
    float latv[4];
    #pragma unroll
    for (int j = 0; j < 4; j++) {
        int t = tq + j;
        const float4* wr = (const float4*)(fw + t*16);
        float4 w0=wr[0], w1=wr[1], w2=wr[2], w3=wr[3];
        float l = fb[t];
        l += s0.x*w0.x + s0.y*w0.y + s0.z*w0.z + s0.w*w0.w;
        l += s1.x*w1.x + s1.y*w1.y + s1.z*w1.z + s1.w*w1.w;
        l += s2.x*w2.x + s2.y*w2.y + s2.z*w2.z + s2.w*w2.w;
        l += s3.x*w3.x + s3.y*w3.y + s3.z*w3.z + s3.w*w3.w;
        latv[j] = l;
    }
    float dv[4];
    #pragma unroll
    for (int j = 0; j < 4; j++) {
        float xx = fminf(fmaxf(impv[j], -8.f), 8.f);
        float f = (xx + 8.f) * 128.f;
        float fi = floorf(f);
        int i = (int)fi; i = i > NTAB-2 ? NTAB-2 : i;
        float w = f - fi;
        dv[j] = fmaf(w, tab[i+1] - tab[i], tab[i]);
    }
    float4 rv = ((const float4*)rec)[q];
    size_t eo = (size_t)b*16 + tq;
    *(float4*)(out + eo)        = make_float4(impv[0], impv[1], impv[2], impv[3]);
    *(float4*)(out + BS + eo)   = make_float4(dv[0], dv[1], dv[2], dv[3]);
    *(float4*)(out + 2*BS + eo) = make_float4(latv[0], latv[1], latv[2], latv[3]);
    *(float4*)(out + 3*BS + eo) = rv;
}

extern "C" void kernel_launch(void* const* d_in, const int* in_sizes, int n_in,
                              void* d_out, int out_size, void* d_ws, size_t ws_size,
                              hipStream_t stream)
{
    float* ws = (float*)d_ws;
    P29 a;
    for (int i = 0; i < 29; i++) a.p[i] = (const float*)d_in[i];
    const int* masks = (const int*)d_in[1];
    k_main<<<NSCAN + NTABB + 1, 256, 0, stream>>>(a, masks, ws);  // scan ∥ table ∥ decoder
    k_post<<<(BB*4)/256, 256, 0, stream>>>(a, masks, ws, (float*)d_out);
}

// Round 6
// 153.971 us; speedup vs baseline: 1.0099x; 1.0099x over previous
//
#include <hip/hip_runtime.h>

#define BB 32768
#define BS (BB*16)   // 524288

typedef __attribute__((ext_vector_type(8))) short bf8v;   // 8 bf16 (4 VGPRs)
typedef __attribute__((ext_vector_type(4))) float f4v;

// ---- ws float offsets ----
#define RECO 64
#define TAB  128             // disc F table, 2049 floats over [-8,8], step 1/128
#define NTAB 2049
#define HFO  8448
#define HBO  (HFO+BS)

// ---- table-path LDS layout (USHORT indices; weights stored bf16) ----
#define PW0 0
#define PB0 96
#define PW1 192    // 48 rows x 36
#define PB1 1920
#define PW2 1968   // 24 x 20
#define PB2 2448
#define PW3 2472   // 48 x 12
#define PB3 3048
#define PW4 3096   // 96 x 20
#define PB4 5016
#define POW 5112
#define POB 5144
#define PNU 5148             // ushorts = 10.3KB

#define SMF 2580             // floats: 10320 B >= table's 10296 B; scan uses 0

#define NSCAN 512            // scan blocks; each wave runs 2 independent chains
#define NTABB 129
// blocks 0..511 = scan (2 tiles/wave), 512..640 = table, 641 = decoder

__device__ __forceinline__ float sigm(float x){
    return __builtin_amdgcn_rcpf(1.f + __expf(-x));
}
__device__ __forceinline__ float tanh_f(float x){
    return 1.f - 2.f * __builtin_amdgcn_rcpf(1.f + __expf(2.f * x));
}
__device__ __forceinline__ float dunit(float gi, float gg, float go){
    return sigm(go) * tanh_f(sigm(gi) * tanh_f(gg));
}
__device__ __forceinline__ unsigned short f2bf(float f){   // RNE
    union { float f; unsigned int i; } v; v.f = f;
    unsigned int x = v.i;
    unsigned int r = x + 0x7fffu + ((x >> 16) & 1u);
    return (unsigned short)(r >> 16);
}
__device__ __forceinline__ float bfu(unsigned short s){
    union { unsigned u; float f; } v; v.u = ((unsigned)s) << 16; return v.f;
}
__device__ __forceinline__ float bflo(unsigned p){
    union { unsigned u; float f; } v; v.u = p << 16; return v.f;
}
__device__ __forceinline__ float bfhi(unsigned p){
    union { unsigned u; float f; } v; v.u = p & 0xffff0000u; return v.f;
}

struct P29 { const float* p[29]; };
// 0 values 1 masks 2-4 g_fwd(Wih,Whh,b) 5-7 g_bwd 8 impW 9 impb
// 10 fcW 11 fcb 12-14 dec(Wih,Whh,b) 15 dec_out_W 16 dec_out_b 17 disc_out_W
// 18 disc_out_b 19/20 d_W_0/d_b_0 ... 27/28 d_W_4/d_b_4

// A fragment (R1-validated): W[row][k] at lane: row=lane&15, k=quad*8+j.
// quads 0,1 = Whh row; quad 2, j=0 (k=16) = Wih column (cc enters via the
// B-side patch at the same k-slot).
__device__ __forceinline__ bf8v makeB(const float* Whh, const float* Wih,
                                      int row, int quad)
{
    bf8v B = {0,0,0,0,0,0,0,0};
    if (quad < 2) {
        const float4* p = (const float4*)(Whh + row*16 + quad*8);
        float4 a0 = p[0], a1 = p[1];
        B[0]=(short)f2bf(a0.x); B[1]=(short)f2bf(a0.y);
        B[2]=(short)f2bf(a0.z); B[3]=(short)f2bf(a0.w);
        B[4]=(short)f2bf(a1.x); B[5]=(short)f2bf(a1.y);
        B[6]=(short)f2bf(a1.z); B[7]=(short)f2bf(a1.w);
    } else if (quad == 2) {
        B[0] = (short)f2bf(Wih[row]);
    }
    return B;
}

// ==== k_main: 0..511 MFMA scan | 512..640 disc F table | 641 decoder ====
__global__ __launch_bounds__(256)
void k_main(P29 a, const int* __restrict__ masks, float* __restrict__ ws)
{
    __shared__ __align__(16) float smem[SMF];
    int tid = threadIdx.x;

    if (blockIdx.x < NSCAN) {
        // ------- scan path: R1 dataflow x 2 independent chains per wave -------
        // t4 loop NOT unrolled: keeps the hot body (~4 steps x 2 chains) inside
        // the 32KB I-cache.  Inner j/s loops stay unrolled (static indexing, ILP).
        int lane = tid & 63;
        int wv   = tid >> 6;
        int m    = lane & 15;        // batch column within tile
        int quad = lane >> 4;
        int dir  = (int)(blockIdx.x >= 256);
        int b0   = (blockIdx.x & 255) * 128 + wv * 32;   // 2 tiles: b0, b0+16

        const float* __restrict__ Wih = a.p[2 + 3*dir];
        const float* __restrict__ Whh = a.p[3 + 3*dir];
        const float* __restrict__ bia = a.p[4 + 3*dir];

        // A operands (shared by both chains)
        bf8v Ai = makeB(Whh, Wih, m,      quad);
        bf8v Af = makeB(Whh, Wih, 16+m,   quad);
        bf8v Ag = makeB(Whh, Wih, 32+m,   quad);
        bf8v Ao = makeB(Whh, Wih, 48+m,   quad);
        bf8v Ap = {0,0,0,0,0,0,0,0};
        if (quad < 2) {
            const float4* p = (const float4*)(a.p[8] + quad*8);
            float4 a0 = p[0], a1 = p[1];
            Ap[0]=(short)f2bf(a0.x); Ap[1]=(short)f2bf(a0.y);
            Ap[2]=(short)f2bf(a0.z); Ap[3]=(short)f2bf(a0.w);
            Ap[4]=(short)f2bf(a1.x); Ap[5]=(short)f2bf(a1.y);
            Ap[6]=(short)f2bf(a1.z); Ap[7]=(short)f2bf(a1.w);
        }
        float impb = a.p[9][0];
        const f4v cz = {0.f, 0.f, 0.f, 0.f};   // zero C for dimp; impb added in select

        // Gate biases as the MFMA C operand: C[u][m] = b[u], u = quad*4+r
        f4v cbi, cbf, cbg, cbo;
        {
            float4 t;
            t = *(const float4*)(bia +      quad*4); cbi = (f4v){t.x,t.y,t.z,t.w};
            t = *(const float4*)(bia + 16 + quad*4); cbf = (f4v){t.x,t.y,t.z,t.w};
            t = *(const float4*)(bia + 32 + quad*4); cbg = (f4v){t.x,t.y,t.z,t.w};
            t = *(const float4*)(bia + 48 + quad*4); cbo = (f4v){t.x,t.y,t.z,t.w};
        }

        // init cell: x = +-128, h=c=0 -> identical for both chains
        float sgn = dir ? -128.f : 128.f;
        float c[2][4], hl[2][4];
        {
            float4 wI = *(const float4*)(Wih +      quad*4);
            float4 wG = *(const float4*)(Wih + 32 + quad*4);
            float4 wO = *(const float4*)(Wih + 48 + quad*4);
            float wIv[4] = {wI.x, wI.y, wI.z, wI.w};
            float wGv[4] = {wG.x, wG.y, wG.z, wG.w};
            float wOv[4] = {wO.x, wO.y, wO.z, wO.w};
            #pragma unroll
            for (int r = 0; r < 4; r++) {
                float gi0 = sgn*wIv[r] + cbi[r];
                float gg0 = sgn*wGv[r] + cbg[r];
                float go0 = sgn*wOv[r] + cbo[r];
                float c0 = sigm(gi0) * tanh_f(gg0);
                float h0 = sigm(go0) * tanh_f(c0);
                c[0][r] = c0; c[1][r] = c0;
                hl[0][r] = h0; hl[1][r] = h0;
            }
        }
        unsigned u01[2], u23[2];
        #pragma unroll
        for (int s = 0; s < 2; s++) {
            asm("v_cvt_pk_bf16_f32 %0, %1, %2" : "=v"(u01[s]) : "v"(hl[s][0]), "v"(hl[s][1]));
            asm("v_cvt_pk_bf16_f32 %0, %1, %2" : "=v"(u23[s]) : "v"(hl[s][2]), "v"(hl[s][3]));
        }

        // bpermute sources: B word w needs h rows quad*8+2w,+1 -> lanes m+32q, m+32q+16
        int pa0 = ((m + quad*32)      & 63) << 2;
        int pa1 = ((m + quad*32 + 16) & 63) << 2;

        const float* xrow0 = a.p[0] + (size_t)(b0 + m) * 16;
        const int*   mrow0 = masks  + (size_t)(b0 + m) * 16;
        const float* xrow1 = xrow0 + 16*16;
        const int*   mrow1 = mrow0 + 16*16;

        #pragma unroll 1
        for (int t4 = 0; t4 < 4; t4++) {
            float4 xv0 = *(const float4*)(xrow0 + t4*4);
            int4   mv0 = *(const int4*)(mrow0 + t4*4);
            float4 xv1 = *(const float4*)(xrow1 + t4*4);
            int4   mv1 = *(const int4*)(mrow1 + t4*4);
            float xa[2][4] = {{xv0.x, xv0.y, xv0.z, xv0.w},
                              {xv1.x, xv1.y, xv1.z, xv1.w}};
            int   ma[2][4] = {{mv0.x, mv0.y, mv0.z, mv0.w},
                              {mv1.x, mv1.y, mv1.z, mv1.w}};
            #pragma unroll
            for (int j = 0; j < 4; j++) {
                union U4 { int i[4]; bf8v v; } B[2];
                #pragma unroll
                for (int s = 0; s < 2; s++) {
                    int w0 = __builtin_amdgcn_ds_bpermute(pa0, (int)u01[s]);
                    int w1 = __builtin_amdgcn_ds_bpermute(pa0, (int)u23[s]);
                    int w2 = __builtin_amdgcn_ds_bpermute(pa1, (int)u01[s]);
                    int w3 = __builtin_amdgcn_ds_bpermute(pa1, (int)u23[s]);
                    bool hi2 = quad >= 2;
                    B[s].i[0] = hi2 ? 0 : w0;
                    B[s].i[1] = hi2 ? 0 : w1;
                    B[s].i[2] = hi2 ? 0 : w2;
                    B[s].i[3] = hi2 ? 0 : w3;
                }
                #pragma unroll
                for (int s = 0; s < 2; s++) {
                    f4v dimp = __builtin_amdgcn_mfma_f32_16x16x32_bf16(Ap, B[s].v, cz, 0, 0, 0);
                    float cc = ma[s][j] ? (dimp[0] + impb) : xa[s][j];
                    unsigned ccw;
                    asm("v_cvt_pk_bf16_f32 %0, %1, %2" : "=v"(ccw) : "v"(cc), "v"(0.f));
                    if (quad == 2) B[s].i[0] = (int)ccw;   // cc at k=16
                    f4v di  = __builtin_amdgcn_mfma_f32_16x16x32_bf16(Ai, B[s].v, cbi, 0, 0, 0);
                    f4v df_ = __builtin_amdgcn_mfma_f32_16x16x32_bf16(Af, B[s].v, cbf, 0, 0, 0);
                    f4v dg  = __builtin_amdgcn_mfma_f32_16x16x32_bf16(Ag, B[s].v, cbg, 0, 0, 0);
                    f4v dO  = __builtin_amdgcn_mfma_f32_16x16x32_bf16(Ao, B[s].v, cbo, 0, 0, 0);
                    #pragma unroll
                    for (int r = 0; r < 4; r++) {
                        float cn = sigm(df_[r])*c[s][r] + sigm(di[r])*tanh_f(dg[r]);
                        c[s][r] = cn;
                        hl[s][r] = sigm(dO[r])*tanh_f(cn);
                    }
                    asm("v_cvt_pk_bf16_f32 %0, %1, %2" : "=v"(u01[s]) : "v"(hl[s][0]), "v"(hl[s][1]));
                    asm("v_cvt_pk_bf16_f32 %0, %1, %2" : "=v"(u23[s]) : "v"(hl[s][2]), "v"(hl[s][3]));
                }
            }
        }
        // final h: lane holds h[u=quad*4+r][m] -> ws[... + m*16 + u]
        float* outp = ws + HFO + (size_t)dir*BS + (size_t)b0*16;
        #pragma unroll
        for (int r = 0; r < 4; r++) {
            outp[m*16 + quad*4 + r]        = hl[0][r];
            outp[(16 + m)*16 + quad*4 + r] = hl[1][r];
        }
        return;
    }

    if (blockIdx.x < NSCAN + NTABB) {
        // -------- F-table path: bf16 weights in LDS (10.3KB), 16 lanes/entry --------
        unsigned short* wl = (unsigned short*)smem;
#define STAGE(WS, BSi, h, K, padK, wdst, bdst) \
    { const float* Wp = a.p[WS]; const float* Bp2 = a.p[BSi]; \
      for (int i = tid; i < 3*(h)*(K); i += 256){ \
        int r = i/(K), k = i - r*(K); int g = r/(h), u0 = r - g*(h); \
        int sr = (g==0? u0 : (g==1? 2*(h)+u0 : 3*(h)+u0)); \
        wl[(wdst) + r*(padK) + k] = f2bf(Wp[sr*(K) + k]); } \
      for (int i = tid; i < 3*(h); i += 256){ \
        int g = i/(h), u0 = i - g*(h); \
        int sr = (g==0? u0 : (g==1? 2*(h)+u0 : 3*(h)+u0)); \
        wl[(bdst) + i] = f2bf(Bp2[sr]); } }
        STAGE(19, 20, 32,  1,  1, PW0, PB0)
        STAGE(21, 22, 16, 32, 36, PW1, PB1)
        STAGE(23, 24,  8, 16, 20, PW2, PB2)
        STAGE(25, 26, 16,  8, 12, PW3, PB3)
        STAGE(27, 28, 32, 16, 20, PW4, PB4)
#undef STAGE
        { const float* s = a.p[17]; for (int i = tid; i < 32; i += 256) wl[POW+i] = f2bf(s[i]); }
        if (tid == 0) wl[POB] = f2bf(a.p[18][0]);
        __syncthreads();
        int u = tid & 15;
        int gbase = (tid & 63) & 48;
        int gid = (blockIdx.x - NSCAN) * 16 + (tid >> 4);
        const uint2* w2 = (const uint2*)wl;      // index = ushort_idx/4
        float xin = -8.f + (float)gid * (1.f/128.f);
        float lo = dunit(xin*bfu(wl[PW0+u])    + bfu(wl[PB0+u]),
                         xin*bfu(wl[PW0+32+u]) + bfu(wl[PB0+32+u]),
                         xin*bfu(wl[PW0+64+u]) + bfu(wl[PB0+64+u]));
        float hi = dunit(xin*bfu(wl[PW0+16+u]) + bfu(wl[PB0+16+u]),
                         xin*bfu(wl[PW0+48+u]) + bfu(wl[PB0+48+u]),
                         xin*bfu(wl[PW0+80+u]) + bfu(wl[PB0+80+u]));
        float A0[32];
        #pragma unroll
        for (int k = 0; k < 16; k++) { A0[k] = __shfl(lo, gbase+k); A0[16+k] = __shfl(hi, gbase+k); }
        float gi = bfu(wl[PB1+u]), gg = bfu(wl[PB1+16+u]), go = bfu(wl[PB1+32+u]);
        int bi_ = (PW1 + u*36)>>2, bg_ = (PW1 + (16+u)*36)>>2, bo_ = (PW1 + (32+u)*36)>>2;
        #pragma unroll
        for (int q = 0; q < 8; q++) {
            uint2 wi = w2[bi_+q], wg = w2[bg_+q], wo = w2[bo_+q];
            float b0=A0[4*q], b1=A0[4*q+1], b2=A0[4*q+2], b3=A0[4*q+3];
            gi += b0*bflo(wi.x) + b1*bfhi(wi.x) + b2*bflo(wi.y) + b3*bfhi(wi.y);
            gg += b0*bflo(wg.x) + b1*bfhi(wg.x) + b2*bflo(wg.y) + b3*bfhi(wg.y);
            go += b0*bflo(wo.x) + b1*bfhi(wo.x) + b2*bflo(wo.y) + b3*bfhi(wo.y);
        }
        float a1 = dunit(gi, gg, go);
        float A1[16];
        #pragma unroll
        for (int k = 0; k < 16; k++) A1[k] = __shfl(a1, gbase+k);
        int v = u & 7;
        gi = bfu(wl[PB2+v]); gg = bfu(wl[PB2+8+v]); go = bfu(wl[PB2+16+v]);
        bi_ = (PW2 + v*20)>>2; bg_ = (PW2 + (8+v)*20)>>2; bo_ = (PW2 + (16+v)*20)>>2;
        #pragma unroll
        for (int q = 0; q < 4; q++) {
            uint2 wi = w2[bi_+q], wg = w2[bg_+q], wo = w2[bo_+q];
            float b0=A1[4*q], b1=A1[4*q+1], b2=A1[4*q+2], b3=A1[4*q+3];
            gi += b0*bflo(wi.x) + b1*bfhi(wi.x) + b2*bflo(wi.y) + b3*bfhi(wi.y);
            gg += b0*bflo(wg.x) + b1*bfhi(wg.x) + b2*bflo(wg.y) + b3*bfhi(wg.y);
            go += b0*bflo(wo.x) + b1*bfhi(wo.x) + b2*bflo(wo.y) + b3*bfhi(wo.y);
        }
        float a2 = dunit(gi, gg, go);
        float A2[8];
        #pragma unroll
        for (int k = 0; k < 8; k++) A2[k] = __shfl(a2, gbase+k);
        gi = bfu(wl[PB3+u]); gg = bfu(wl[PB3+16+u]); go = bfu(wl[PB3+32+u]);
        bi_ = (PW3 + u*12)>>2; bg_ = (PW3 + (16+u)*12)>>2; bo_ = (PW3 + (32+u)*12)>>2;
        #pragma unroll
        for (int q = 0; q < 2; q++) {
            uint2 wi = w2[bi_+q], wg = w2[bg_+q], wo = w2[bo_+q];
            float b0=A2[4*q], b1=A2[4*q+1], b2=A2[4*q+2], b3=A2[4*q+3];
            gi += b0*bflo(wi.x) + b1*bfhi(wi.x) + b2*bflo(wi.y) + b3*bfhi(wi.y);
            gg += b0*bflo(wg.x) + b1*bfhi(wg.x) + b2*bflo(wg.y) + b3*bfhi(wg.y);
            go += b0*bflo(wo.x) + b1*bfhi(wo.x) + b2*bflo(wo.y) + b3*bfhi(wo.y);
        }
        float a3 = dunit(gi, gg, go);
        float A3[16];
        #pragma unroll
        for (int k = 0; k < 16; k++) A3[k] = __shfl(a3, gbase+k);
        float part;
        {
            float g0i = bfu(wl[PB4+u]),    g0g = bfu(wl[PB4+32+u]), g0o = bfu(wl[PB4+64+u]);
            float g1i = bfu(wl[PB4+16+u]), g1g = bfu(wl[PB4+48+u]), g1o = bfu(wl[PB4+80+u]);
            int c0i = (PW4 + u*20)>>2,      c0g = (PW4 + (32+u)*20)>>2, c0o = (PW4 + (64+u)*20)>>2;
            int c1i = (PW4 + (16+u)*20)>>2, c1g = (PW4 + (48+u)*20)>>2, c1o = (PW4 + (80+u)*20)>>2;
            #pragma unroll
            for (int q = 0; q < 4; q++) {
                float b0=A3[4*q], b1=A3[4*q+1], b2=A3[4*q+2], b3=A3[4*q+3];
                uint2 wi = w2[c0i+q], wg = w2[c0g+q], wo = w2[c0o+q];
                g0i += b0*bflo(wi.x) + b1*bfhi(wi.x) + b2*bflo(wi.y) + b3*bfhi(wi.y);
                g0g += b0*bflo(wg.x) + b1*bfhi(wg.x) + b2*bflo(wg.y) + b3*bfhi(wg.y);
                g0o += b0*bflo(wo.x) + b1*bfhi(wo.x) + b2*bflo(wo.y) + b3*bfhi(wo.y);
                wi = w2[c1i+q]; wg = w2[c1g+q]; wo = w2[c1o+q];
                g1i += b0*bflo(wi.x) + b1*bfhi(wi.x) + b2*bflo(wi.y) + b3*bfhi(wi.y);
                g1g += b0*bflo(wg.x) + b1*bfhi(wg.x) + b2*bflo(wg.y) + b3*bfhi(wg.y);
                g1o += b0*bflo(wo.x) + b1*bfhi(wo.x) + b2*bflo(wo.y) + b3*bfhi(wo.y);
            }
            part = dunit(g0i, g0g, g0o)*bfu(wl[POW+u]) + dunit(g1i, g1g, g1o)*bfu(wl[POW+16+u]);
        }
        part += __shfl_xor(part, 1);
        part += __shfl_xor(part, 2);
        part += __shfl_xor(part, 4);
        part += __shfl_xor(part, 8);
        if (u == 0 && gid < NTAB) ws[TAB + gid] = part + bfu(wl[POB]);
        return;
    }

    // ---------------- decoder block (batch-invariant scan) ----------------
    {
        float* dh = smem;
        float* dc = smem + 16;
        const float* Wih = a.p[12];
        const float* Whh = a.p[13];
        const float* bb  = a.p[14];
        const float* oW  = a.p[15];
        const float* ob  = a.p[16];
        float wii[16], wff[16], wgg[16], woo[16];
        float vii[16], vff[16], vgg[16], voo[16];
        float bi_r=0, bf_r=0, bg_r=0, bo_r=0;
        if (tid < 16) {
            int uu = tid;
            #pragma unroll
            for (int k = 0; k < 16; k++) {
                wii[k]=Wih[uu*16+k];      vii[k]=Whh[uu*16+k];
                wff[k]=Wih[(16+uu)*16+k]; vff[k]=Whh[(16+uu)*16+k];
                wgg[k]=Wih[(32+uu)*16+k]; vgg[k]=Whh[(32+uu)*16+k];
                woo[k]=Wih[(48+uu)*16+k]; voo[k]=Whh[(48+uu)*16+k];
            }
            bi_r=bb[uu]; bf_r=bb[16+uu]; bg_r=bb[32+uu]; bo_r=bb[48+uu];
            float gi = bi_r, gg = bg_r, go = bo_r;
            #pragma unroll
            for (int k = 0; k < 16; k++) {
                gi += 128.f * wii[k];
                gg += 128.f * wgg[k];
                go += 128.f * woo[k];
            }
            float cd0 = sigm(gi) * tanh_f(gg);
            dc[tid] = cd0; dh[tid] = sigm(go) * tanh_f(cd0);
        }
        __syncthreads();
        for (int t = 0; t < 16; t++) {
            float rx[16], rh[16], cold = 0.f;
            if (tid < 16) {
                #pragma unroll
                for (int k = 0; k < 16; k++) { rx[k] = dc[k]; rh[k] = dh[k]; }
                cold = dc[tid];
            }
            __syncthreads();
            if (tid < 16) {
                float gi = bi_r, gf = bf_r, gg = bg_r, go = bo_r;
                #pragma unroll
                for (int k = 0; k < 16; k++) {
                    gi += rx[k]*wii[k] + rh[k]*vii[k];
                    gf += rx[k]*wff[k] + rh[k]*vff[k];
                    gg += rx[k]*wgg[k] + rh[k]*vgg[k];
                    go += rx[k]*woo[k] + rh[k]*voo[k];
                }
                float cn = sigm(gf)*cold + sigm(gi)*tanh_f(gg);
                dc[tid] = cn; dh[tid] = sigm(go)*tanh_f(cn);
            }
            __syncthreads();
            if (tid == 0) {
                float o = ob[0];
                #pragma unroll
                for (int k = 0; k < 16; k++) o += dh[k] * oW[k];
                ws[RECO + t] = o;
            }
            __syncthreads();
        }
    }
}

// ---- k_post: 4 elements per thread; fcW/rec/table staged in LDS ----
__global__ __launch_bounds__(256) void k_post(P29 a, const int* __restrict__ masks,
                                              const float* __restrict__ ws,
                                              float* __restrict__ out)
{
    __shared__ float tab[NTAB];
    __shared__ __align__(16) float fw[256];
    __shared__ __align__(16) float rec[16];
    __shared__ float fb[16];
    int tid = threadIdx.x;
    for (int i = tid; i < NTAB; i += 256) tab[i] = ws[TAB + i];
    fw[tid] = a.p[10][tid];
    if (tid < 16) { fb[tid] = a.p[11][tid]; rec[tid] = ws[RECO + tid]; }
    __syncthreads();
    int T = blockIdx.x * 256 + tid;
    int b = T >> 2;
    int q = T & 3;
    int tq = q * 4;
    const float4* hf4 = (const float4*)(ws + HFO + (size_t)b*16);
    const float4* hb4 = (const float4*)(ws + HBO + (size_t)b*16);
    float4 s0, s1, s2, s3;
    {
        float4 f0=hf4[0], f1=hf4[1], f2=hf4[2], f3=hf4[3];
        float4 g0=hb4[0], g1=hb4[1], g2=hb4[2], g3=hb4[3];
        s0 = make_float4(f0.x+g0.x, f0.y+g0.y, f0.z+g0.z, f0.w+g0.w);
        s1 = make_float4(f1.x+g1.x, f1.y+g1.y, f1.z+g1.z, f1.w+g1.w);
        s2 = make_float4(f2.x+g2.x, f2.y+g2.y, f2.z+g2.z, f2.w+g2.w);
        s3 = make_float4(f3.x+g3.x, f3.y+g3.y, f3.z+g3.z, f3.w+g3.w);
    }
    float4 hq = (q==0) ? s0 : (q==1) ? s1 : (q==2) ? s2 : s3;
    float4 xv = *(const float4*)(a.p[0] + (size_t)b*16 + tq);
    int4   mv = *(const int4*)(masks + (size_t)b*16 + tq);
    float impv[4];
    impv[0] = mv.x ? xv.x : hq.x;
    impv[1] = mv.y ? xv.y : hq.y;
    impv[2] = mv.z ? xv.z : hq.z;
    impv[3] = mv.w ? xv.w : hq.w;
    float latv[4];
    #pragma unroll
    for (int j = 0; j < 4; j++) {
        int t = tq + j;
        const float4* wr = (const float4*)(fw + t*16);
        float4 w0=wr[0], w1=wr[1], w2=wr[2], w3=wr[3];
        float l = fb[t];
        l += s0.x*w0.x + s0.y*w0.y + s0.z*w0.z + s0.w*w0.w;
        l += s1.x*w1.x + s1.y*w1.y + s1.z*w1.z + s1.w*w1.w;
        l += s2.x*w2.x + s2.y*w2.y + s2.z*w2.z + s2.w*w2.w;
        l += s3.x*w3.x + s3.y*w3.y + s3.z*w3.z + s3.w*w3.w;
        latv[j] = l;
    }
    float dv[4];
    #pragma unroll
    for (int j = 0; j < 4; j++) {
        float xx = fminf(fmaxf(impv[j], -8.f), 8.f);
        float f = (xx + 8.f) * 128.f;
        float fi = floorf(f);
        int i = (int)fi; i = i > NTAB-2 ? NTAB-2 : i;
        float w = f - fi;
        dv[j] = fmaf(w, tab[i+1] - tab[i], tab[i]);
    }
    float4 rv = ((const float4*)rec)[q];
    size_t eo = (size_t)b*16 + tq;
    *(float4*)(out + eo)        = make_float4(impv[0], impv[1], impv[2], impv[3]);
    *(float4*)(out + BS + eo)   = make_float4(dv[0], dv[1], dv[2], dv[3]);
    *(float4*)(out + 2*BS + eo) = make_float4(latv[0], latv[1], latv[2], latv[3]);
    *(float4*)(out + 3*BS + eo) = rv;
}

extern "C" void kernel_launch(void* const* d_in, const int* in_sizes, int n_in,
                              void* d_out, int out_size, void* d_ws, size_t ws_size,
                              hipStream_t stream)
{
    float* ws = (float*)d_ws;
    P29 a;
    for (int i = 0; i < 29; i++) a.p[i] = (const float*)d_in[i];
    const int* masks = (const int*)d_in[1];
    k_main<<<NSCAN + NTABB + 1, 256, 0, stream>>>(a, masks, ws);  // scan ∥ table ∥ decoder
    k_post<<<(BB*4)/256, 256, 0, stream>>>(a, masks, ws, (float*)d_out);
}

// Round 7
// 148.656 us; speedup vs baseline: 1.0460x; 1.0357x over previous
//
#include <hip/hip_runtime.h>

#define BB 32768
#define BS (BB*16)   // 524288

typedef __attribute__((ext_vector_type(8))) short bf8v;   // 8 bf16 (4 VGPRs)
typedef __attribute__((ext_vector_type(4))) float f4v;

// ---- ws float offsets ----
#define RECO 64
#define TAB  128             // disc F table, 2049 floats over [-8,8], step 1/128
#define NTAB 2049
#define HFO  8448
#define HBO  (HFO+BS)

// ---- table-path LDS layout (USHORT indices; weights stored bf16) ----
#define PW0 0
#define PB0 96
#define PW1 192    // 48 rows x 36
#define PB1 1920
#define PW2 1968   // 24 x 20
#define PB2 2448
#define PW3 2472   // 48 x 12
#define PB3 3048
#define PW4 3096   // 96 x 20
#define PB4 5016
#define POW 5112
#define POB 5144
#define PNU 5148             // ushorts = 10.3KB

#define SMF 2580             // floats: 10320 B >= table's 10296 B; scan uses 0

#define NSCAN 256            // scan blocks; each wave runs 4 independent chains
#define NTABB 129
// blocks 0..255 = scan (4 tiles/wave, 1 block/CU), 256..384 = table, 385 = decoder

__device__ __forceinline__ float sigm(float x){
    return __builtin_amdgcn_rcpf(1.f + __expf(-x));
}
__device__ __forceinline__ float tanh_f(float x){
    return 1.f - 2.f * __builtin_amdgcn_rcpf(1.f + __expf(2.f * x));
}
__device__ __forceinline__ float dunit(float gi, float gg, float go){
    return sigm(go) * tanh_f(sigm(gi) * tanh_f(gg));
}
__device__ __forceinline__ unsigned short f2bf(float f){   // RNE
    union { float f; unsigned int i; } v; v.f = f;
    unsigned int x = v.i;
    unsigned int r = x + 0x7fffu + ((x >> 16) & 1u);
    return (unsigned short)(r >> 16);
}
__device__ __forceinline__ float bfu(unsigned short s){
    union { unsigned u; float f; } v; v.u = ((unsigned)s) << 16; return v.f;
}
__device__ __forceinline__ float bflo(unsigned p){
    union { unsigned u; float f; } v; v.u = p << 16; return v.f;
}
__device__ __forceinline__ float bfhi(unsigned p){
    union { unsigned u; float f; } v; v.u = p & 0xffff0000u; return v.f;
}

struct P29 { const float* p[29]; };
// 0 values 1 masks 2-4 g_fwd(Wih,Whh,b) 5-7 g_bwd 8 impW 9 impb
// 10 fcW 11 fcb 12-14 dec(Wih,Whh,b) 15 dec_out_W 16 dec_out_b 17 disc_out_W
// 18 disc_out_b 19/20 d_W_0/d_b_0 ... 27/28 d_W_4/d_b_4

// A fragment (R1-validated): W[row][k] at lane: row=lane&15, k=quad*8+j.
// quads 0,1 = Whh row; quad 2, j=0 (k=16) = Wih column (cc enters via the
// B-side patch at the same k-slot).
__device__ __forceinline__ bf8v makeB(const float* Whh, const float* Wih,
                                      int row, int quad)
{
    bf8v B = {0,0,0,0,0,0,0,0};
    if (quad < 2) {
        const float4* p = (const float4*)(Whh + row*16 + quad*8);
        float4 a0 = p[0], a1 = p[1];
        B[0]=(short)f2bf(a0.x); B[1]=(short)f2bf(a0.y);
        B[2]=(short)f2bf(a0.z); B[3]=(short)f2bf(a0.w);
        B[4]=(short)f2bf(a1.x); B[5]=(short)f2bf(a1.y);
        B[6]=(short)f2bf(a1.z); B[7]=(short)f2bf(a1.w);
    } else if (quad == 2) {
        B[0] = (short)f2bf(Wih[row]);
    }
    return B;
}

// ==== k_main: 0..255 MFMA scan | 256..384 disc F table | 385 decoder ====
// launch_bounds(256,1): allow up to ~512 VGPR so 4 interleaved chains never spill.
__global__ __launch_bounds__(256, 1)
void k_main(P29 a, const int* __restrict__ masks, float* __restrict__ ws)
{
    __shared__ __align__(16) float smem[SMF];
    int tid = threadIdx.x;

    if (blockIdx.x < NSCAN) {
        // ---- scan path: R4-verified dataflow x 4 independent chains per wave ----
        // All 4 chains of a SIMD live in ONE instruction stream: the compiler
        // statically interleaves them, so each chain's bpermute/MFMA/trans
        // latency is filled by the other three chains' instructions.
        int lane = tid & 63;
        int wv   = tid >> 6;
        int m    = lane & 15;        // batch column within tile
        int quad = lane >> 4;
        int dir  = (int)(blockIdx.x >= 128);
        int b0   = (blockIdx.x & 127) * 256 + wv * 64;   // 4 tiles: b0+16*s

        const float* __restrict__ Wih = a.p[2 + 3*dir];
        const float* __restrict__ Whh = a.p[3 + 3*dir];
        const float* __restrict__ bia = a.p[4 + 3*dir];

        // A operands (shared by all chains)
        bf8v Ai = makeB(Whh, Wih, m,      quad);
        bf8v Af = makeB(Whh, Wih, 16+m,   quad);
        bf8v Ag = makeB(Whh, Wih, 32+m,   quad);
        bf8v Ao = makeB(Whh, Wih, 48+m,   quad);
        bf8v Ap = {0,0,0,0,0,0,0,0};
        if (quad < 2) {
            const float4* p = (const float4*)(a.p[8] + quad*8);
            float4 a0 = p[0], a1 = p[1];
            Ap[0]=(short)f2bf(a0.x); Ap[1]=(short)f2bf(a0.y);
            Ap[2]=(short)f2bf(a0.z); Ap[3]=(short)f2bf(a0.w);
            Ap[4]=(short)f2bf(a1.x); Ap[5]=(short)f2bf(a1.y);
            Ap[6]=(short)f2bf(a1.z); Ap[7]=(short)f2bf(a1.w);
        }
        float impb = a.p[9][0];
        const f4v cz = {0.f, 0.f, 0.f, 0.f};   // zero C for dimp; impb added in select

        // Gate biases as the MFMA C operand: C[u][m] = b[u], u = quad*4+r
        f4v cbi, cbf, cbg, cbo;
        {
            float4 t;
            t = *(const float4*)(bia +      quad*4); cbi = (f4v){t.x,t.y,t.z,t.w};
            t = *(const float4*)(bia + 16 + quad*4); cbf = (f4v){t.x,t.y,t.z,t.w};
            t = *(const float4*)(bia + 32 + quad*4); cbg = (f4v){t.x,t.y,t.z,t.w};
            t = *(const float4*)(bia + 48 + quad*4); cbo = (f4v){t.x,t.y,t.z,t.w};
        }

        // init cell: x = +-128, h=c=0 -> identical for all chains
        float sgn = dir ? -128.f : 128.f;
        float c[4][4], hl[4][4];
        {
            float4 wI = *(const float4*)(Wih +      quad*4);
            float4 wG = *(const float4*)(Wih + 32 + quad*4);
            float4 wO = *(const float4*)(Wih + 48 + quad*4);
            float wIv[4] = {wI.x, wI.y, wI.z, wI.w};
            float wGv[4] = {wG.x, wG.y, wG.z, wG.w};
            float wOv[4] = {wO.x, wO.y, wO.z, wO.w};
            #pragma unroll
            for (int r = 0; r < 4; r++) {
                float gi0 = sgn*wIv[r] + cbi[r];
                float gg0 = sgn*wGv[r] + cbg[r];
                float go0 = sgn*wOv[r] + cbo[r];
                float c0 = sigm(gi0) * tanh_f(gg0);
                float h0 = sigm(go0) * tanh_f(c0);
                #pragma unroll
                for (int s = 0; s < 4; s++) { c[s][r] = c0; hl[s][r] = h0; }
            }
        }
        unsigned u01[4], u23[4];
        #pragma unroll
        for (int s = 0; s < 4; s++) {
            asm("v_cvt_pk_bf16_f32 %0, %1, %2" : "=v"(u01[s]) : "v"(hl[s][0]), "v"(hl[s][1]));
            asm("v_cvt_pk_bf16_f32 %0, %1, %2" : "=v"(u23[s]) : "v"(hl[s][2]), "v"(hl[s][3]));
        }

        // bpermute sources: B word w needs h rows quad*8+2w,+1 -> lanes m+32q, m+32q+16
        int pa0 = ((m + quad*32)      & 63) << 2;
        int pa1 = ((m + quad*32 + 16) & 63) << 2;

        const float* xr[4];
        const int*   mr[4];
        #pragma unroll
        for (int s = 0; s < 4; s++) {
            xr[s] = a.p[0] + (size_t)(b0 + 16*s + m) * 16;
            mr[s] = masks  + (size_t)(b0 + 16*s + m) * 16;
        }

        #pragma unroll 1
        for (int t4 = 0; t4 < 4; t4++) {
            float xa[4][4];
            int   ma[4][4];
            #pragma unroll
            for (int s = 0; s < 4; s++) {
                float4 xv = *(const float4*)(xr[s] + t4*4);
                int4   mv = *(const int4*)(mr[s] + t4*4);
                xa[s][0]=xv.x; xa[s][1]=xv.y; xa[s][2]=xv.z; xa[s][3]=xv.w;
                ma[s][0]=mv.x; ma[s][1]=mv.y; ma[s][2]=mv.z; ma[s][3]=mv.w;
            }
            #pragma unroll
            for (int j = 0; j < 4; j++) {
                union U4 { int i[4]; bf8v v; } B[4];
                #pragma unroll
                for (int s = 0; s < 4; s++) {
                    int w0 = __builtin_amdgcn_ds_bpermute(pa0, (int)u01[s]);
                    int w1 = __builtin_amdgcn_ds_bpermute(pa0, (int)u23[s]);
                    int w2 = __builtin_amdgcn_ds_bpermute(pa1, (int)u01[s]);
                    int w3 = __builtin_amdgcn_ds_bpermute(pa1, (int)u23[s]);
                    bool hi2 = quad >= 2;
                    B[s].i[0] = hi2 ? 0 : w0;
                    B[s].i[1] = hi2 ? 0 : w1;
                    B[s].i[2] = hi2 ? 0 : w2;
                    B[s].i[3] = hi2 ? 0 : w3;
                }
                #pragma unroll
                for (int s = 0; s < 4; s++) {
                    f4v dimp = __builtin_amdgcn_mfma_f32_16x16x32_bf16(Ap, B[s].v, cz, 0, 0, 0);
                    float cc = ma[s][j] ? (dimp[0] + impb) : xa[s][j];
                    unsigned ccw;
                    asm("v_cvt_pk_bf16_f32 %0, %1, %2" : "=v"(ccw) : "v"(cc), "v"(0.f));
                    if (quad == 2) B[s].i[0] = (int)ccw;   // cc at k=16
                    f4v di  = __builtin_amdgcn_mfma_f32_16x16x32_bf16(Ai, B[s].v, cbi, 0, 0, 0);
                    f4v df_ = __builtin_amdgcn_mfma_f32_16x16x32_bf16(Af, B[s].v, cbf, 0, 0, 0);
                    f4v dg  = __builtin_amdgcn_mfma_f32_16x16x32_bf16(Ag, B[s].v, cbg, 0, 0, 0);
                    f4v dO  = __builtin_amdgcn_mfma_f32_16x16x32_bf16(Ao, B[s].v, cbo, 0, 0, 0);
                    #pragma unroll
                    for (int r = 0; r < 4; r++) {
                        float cn = sigm(df_[r])*c[s][r] + sigm(di[r])*tanh_f(dg[r]);
                        c[s][r] = cn;
                        hl[s][r] = sigm(dO[r])*tanh_f(cn);
                    }
                    asm("v_cvt_pk_bf16_f32 %0, %1, %2" : "=v"(u01[s]) : "v"(hl[s][0]), "v"(hl[s][1]));
                    asm("v_cvt_pk_bf16_f32 %0, %1, %2" : "=v"(u23[s]) : "v"(hl[s][2]), "v"(hl[s][3]));
                }
            }
        }
        // final h: lane holds h[u=quad*4+r][m] for chain s -> ws[... + (16s+m)*16 + u]
        float* outp = ws + HFO + (size_t)dir*BS + (size_t)b0*16;
        #pragma unroll
        for (int s = 0; s < 4; s++)
            #pragma unroll
            for (int r = 0; r < 4; r++)
                outp[(16*s + m)*16 + quad*4 + r] = hl[s][r];
        return;
    }

    if (blockIdx.x < NSCAN + NTABB) {
        // -------- F-table path: bf16 weights in LDS (10.3KB), 16 lanes/entry --------
        unsigned short* wl = (unsigned short*)smem;
#define STAGE(WS, BSi, h, K, padK, wdst, bdst) \
    { const float* Wp = a.p[WS]; const float* Bp2 = a.p[BSi]; \
      for (int i = tid; i < 3*(h)*(K); i += 256){ \
        int r = i/(K), k = i - r*(K); int g = r/(h), u0 = r - g*(h); \
        int sr = (g==0? u0 : (g==1? 2*(h)+u0 : 3*(h)+u0)); \
        wl[(wdst) + r*(padK) + k] = f2bf(Wp[sr*(K) + k]); } \
      for (int i = tid; i < 3*(h); i += 256){ \
        int g = i/(h), u0 = i - g*(h); \
        int sr = (g==0? u0 : (g==1? 2*(h)+u0 : 3*(h)+u0)); \
        wl[(bdst) + i] = f2bf(Bp2[sr]); } }
        STAGE(19, 20, 32,  1,  1, PW0, PB0)
        STAGE(21, 22, 16, 32, 36, PW1, PB1)
        STAGE(23, 24,  8, 16, 20, PW2, PB2)
        STAGE(25, 26, 16,  8, 12, PW3, PB3)
        STAGE(27, 28, 32, 16, 20, PW4, PB4)
#undef STAGE
        { const float* s = a.p[17]; for (int i = tid; i < 32; i += 256) wl[POW+i] = f2bf(s[i]); }
        if (tid == 0) wl[POB] = f2bf(a.p[18][0]);
        __syncthreads();
        int u = tid & 15;
        int gbase = (tid & 63) & 48;
        int gid = (blockIdx.x - NSCAN) * 16 + (tid >> 4);
        const uint2* w2 = (const uint2*)wl;      // index = ushort_idx/4
        float xin = -8.f + (float)gid * (1.f/128.f);
        float lo = dunit(xin*bfu(wl[PW0+u])    + bfu(wl[PB0+u]),
                         xin*bfu(wl[PW0+32+u]) + bfu(wl[PB0+32+u]),
                         xin*bfu(wl[PW0+64+u]) + bfu(wl[PB0+64+u]));
        float hi = dunit(xin*bfu(wl[PW0+16+u]) + bfu(wl[PB0+16+u]),
                         xin*bfu(wl[PW0+48+u]) + bfu(wl[PB0+48+u]),
                         xin*bfu(wl[PW0+80+u]) + bfu(wl[PB0+80+u]));
        float A0[32];
        #pragma unroll
        for (int k = 0; k < 16; k++) { A0[k] = __shfl(lo, gbase+k); A0[16+k] = __shfl(hi, gbase+k); }
        float gi = bfu(wl[PB1+u]), gg = bfu(wl[PB1+16+u]), go = bfu(wl[PB1+32+u]);
        int bi_ = (PW1 + u*36)>>2, bg_ = (PW1 + (16+u)*36)>>2, bo_ = (PW1 + (32+u)*36)>>2;
        #pragma unroll
        for (int q = 0; q < 8; q++) {
            uint2 wi = w2[bi_+q], wg = w2[bg_+q], wo = w2[bo_+q];
            float b0=A0[4*q], b1=A0[4*q+1], b2=A0[4*q+2], b3=A0[4*q+3];
            gi += b0*bflo(wi.x) + b1*bfhi(wi.x) + b2*bflo(wi.y) + b3*bfhi(wi.y);
            gg += b0*bflo(wg.x) + b1*bfhi(wg.x) + b2*bflo(wg.y) + b3*bfhi(wg.y);
            go += b0*bflo(wo.x) + b1*bfhi(wo.x) + b2*bflo(wo.y) + b3*bfhi(wo.y);
        }
        float a1 = dunit(gi, gg, go);
        float A1[16];
        #pragma unroll
        for (int k = 0; k < 16; k++) A1[k] = __shfl(a1, gbase+k);
        int v = u & 7;
        gi = bfu(wl[PB2+v]); gg = bfu(wl[PB2+8+v]); go = bfu(wl[PB2+16+v]);
        bi_ = (PW2 + v*20)>>2; bg_ = (PW2 + (8+v)*20)>>2; bo_ = (PW2 + (16+v)*20)>>2;
        #pragma unroll
        for (int q = 0; q < 4; q++) {
            uint2 wi = w2[bi_+q], wg = w2[bg_+q], wo = w2[bo_+q];
            float b0=A1[4*q], b1=A1[4*q+1], b2=A1[4*q+2], b3=A1[4*q+3];
            gi += b0*bflo(wi.x) + b1*bfhi(wi.x) + b2*bflo(wi.y) + b3*bfhi(wi.y);
            gg += b0*bflo(wg.x) + b1*bfhi(wg.x) + b2*bflo(wg.y) + b3*bfhi(wg.y);
            go += b0*bflo(wo.x) + b1*bfhi(wo.x) + b2*bflo(wo.y) + b3*bfhi(wo.y);
        }
        float a2 = dunit(gi, gg, go);
        float A2[8];
        #pragma unroll
        for (int k = 0; k < 8; k++) A2[k] = __shfl(a2, gbase+k);
        gi = bfu(wl[PB3+u]); gg = bfu(wl[PB3+16+u]); go = bfu(wl[PB3+32+u]);
        bi_ = (PW3 + u*12)>>2; bg_ = (PW3 + (16+u)*12)>>2; bo_ = (PW3 + (32+u)*12)>>2;
        #pragma unroll
        for (int q = 0; q < 2; q++) {
            uint2 wi = w2[bi_+q], wg = w2[bg_+q], wo = w2[bo_+q];
            float b0=A2[4*q], b1=A2[4*q+1], b2=A2[4*q+2], b3=A2[4*q+3];
            gi += b0*bflo(wi.x) + b1*bfhi(wi.x) + b2*bflo(wi.y) + b3*bfhi(wi.y);
            gg += b0*bflo(wg.x) + b1*bfhi(wg.x) + b2*bflo(wg.y) + b3*bfhi(wg.y);
            go += b0*bflo(wo.x) + b1*bfhi(wo.x) + b2*bflo(wo.y) + b3*bfhi(wo.y);
        }
        float a3 = dunit(gi, gg, go);
        float A3[16];
        #pragma unroll
        for (int k = 0; k < 16; k++) A3[k] = __shfl(a3, gbase+k);
        float part;
        {
            float g0i = bfu(wl[PB4+u]),    g0g = bfu(wl[PB4+32+u]), g0o = bfu(wl[PB4+64+u]);
            float g1i = bfu(wl[PB4+16+u]), g1g = bfu(wl[PB4+48+u]), g1o = bfu(wl[PB4+80+u]);
            int c0i = (PW4 + u*20)>>2,      c0g = (PW4 + (32+u)*20)>>2, c0o = (PW4 + (64+u)*20)>>2;
            int c1i = (PW4 + (16+u)*20)>>2, c1g = (PW4 + (48+u)*20)>>2, c1o = (PW4 + (80+u)*20)>>2;
            #pragma unroll
            for (int q = 0; q < 4; q++) {
                float b0=A3[4*q], b1=A3[4*q+1], b2=A3[4*q+2], b3=A3[4*q+3];
                uint2 wi = w2[c0i+q], wg = w2[c0g+q], wo = w2[c0o+q];
                g0i += b0*bflo(wi.x) + b1*bfhi(wi.x) + b2*bflo(wi.y) + b3*bfhi(wi.y);
                g0g += b0*bflo(wg.x) + b1*bfhi(wg.x) + b2*bflo(wg.y) + b3*bfhi(wg.y);
                g0o += b0*bflo(wo.x) + b1*bfhi(wo.x) + b2*bflo(wo.y) + b3*bfhi(wo.y);
                wi = w2[c1i+q]; wg = w2[c1g+q]; wo = w2[c1o+q];
                g1i += b0*bflo(wi.x) + b1*bfhi(wi.x) + b2*bflo(wi.y) + b3*bfhi(wi.y);
                g1g += b0*bflo(wg.x) + b1*bfhi(wg.x) + b2*bflo(wg.y) + b3*bfhi(wg.y);
                g1o += b0*bflo(wo.x) + b1*bfhi(wo.x) + b2*bflo(wo.y) + b3*bfhi(wo.y);
            }
            part = dunit(g0i, g0g, g0o)*bfu(wl[POW+u]) + dunit(g1i, g1g, g1o)*bfu(wl[POW+16+u]);
        }
        part += __shfl_xor(part, 1);
        part += __shfl_xor(part, 2);
        part += __shfl_xor(part, 4);
        part += __shfl_xor(part, 8);
        if (u == 0 && gid < NTAB) ws[TAB + gid] = part + bfu(wl[POB]);
        return;
    }

    // ---------------- decoder block (batch-invariant scan) ----------------
    {
        float* dh = smem;
        float* dc = smem + 16;
        const float* Wih = a.p[12];
        const float* Whh = a.p[13];
        const float* bb  = a.p[14];
        const float* oW  = a.p[15];
        const float* ob  = a.p[16];
        float wii[16], wff[16], wgg[16], woo[16];
        float vii[16], vff[16], vgg[16], voo[16];
        float bi_r=0, bf_r=0, bg_r=0, bo_r=0;
        if (tid < 16) {
            int uu = tid;
            #pragma unroll
            for (int k = 0; k < 16; k++) {
                wii[k]=Wih[uu*16+k];      vii[k]=Whh[uu*16+k];
                wff[k]=Wih[(16+uu)*16+k]; vff[k]=Whh[(16+uu)*16+k];
                wgg[k]=Wih[(32+uu)*16+k]; vgg[k]=Whh[(32+uu)*16+k];
                woo[k]=Wih[(48+uu)*16+k]; voo[k]=Whh[(48+uu)*16+k];
            }
            bi_r=bb[uu]; bf_r=bb[16+uu]; bg_r=bb[32+uu]; bo_r=bb[48+uu];
            float gi = bi_r, gg = bg_r, go = bo_r;
            #pragma unroll
            for (int k = 0; k < 16; k++) {
                gi += 128.f * wii[k];
                gg += 128.f * wgg[k];
                go += 128.f * woo[k];
            }
            float cd0 = sigm(gi) * tanh_f(gg);
            dc[tid] = cd0; dh[tid] = sigm(go) * tanh_f(cd0);
        }
        __syncthreads();
        for (int t = 0; t < 16; t++) {
            float rx[16], rh[16], cold = 0.f;
            if (tid < 16) {
                #pragma unroll
                for (int k = 0; k < 16; k++) { rx[k] = dc[k]; rh[k] = dh[k]; }
                cold = dc[tid];
            }
            __syncthreads();
            if (tid < 16) {
                float gi = bi_r, gf = bf_r, gg = bg_r, go = bo_r;
                #pragma unroll
                for (int k = 0; k < 16; k++) {
                    gi += rx[k]*wii[k] + rh[k]*vii[k];
                    gf += rx[k]*wff[k] + rh[k]*vff[k];
                    gg += rx[k]*wgg[k] + rh[k]*vgg[k];
                    go += rx[k]*woo[k] + rh[k]*voo[k];
                }
                float cn = sigm(gf)*cold + sigm(gi)*tanh_f(gg);
                dc[tid] = cn; dh[tid] = sigm(go)*tanh_f(cn);
            }
            __syncthreads();
            if (tid == 0) {
                float o = ob[0];
                #pragma unroll
                for (int k = 0; k < 16; k++) o += dh[k] * oW[k];
                ws[RECO + t] = o;
            }
            __syncthreads();
        }
    }
}

// ---- k_post: 4 elements per thread; fcW/rec/table staged in LDS ----
__global__ __launch_bounds__(256) void k_post(P29 a, const int* __restrict__ masks,
                                              const float* __restrict__ ws,
                                              float* __restrict__ out)
{
    __shared__ float tab[NTAB];
    __shared__ __align__(16) float fw[256];
    __shared__ __align__(16) float rec[16];
    __shared__ float fb[16];
    int tid = threadIdx.x;
    for (int i = tid; i < NTAB; i += 256) tab[i] = ws[TAB + i];
    fw[tid] = a.p[10][tid];
    if (tid < 16) { fb[tid] = a.p[11][tid]; rec[tid] = ws[RECO + tid]; }
    __syncthreads();
    int T = blockIdx.x * 256 + tid;
    int b = T >> 2;
    int q = T & 3;
    int tq = q * 4;
    const float4* hf4 = (const float4*)(ws + HFO + (size_t)b*16);
    const float4* hb4 = (const float4*)(ws + HBO + (size_t)b*16);
    float4 s0, s1, s2, s3;
    {
        float4 f0=hf4[0], f1=hf4[1], f2=hf4[2], f3=hf4[3];
        float4 g0=hb4[0], g1=hb4[1], g2=hb4[2], g3=hb4[3];
        s0 = make_float4(f0.x+g0.x, f0.y+g0.y, f0.z+g0.z, f0.w+g0.w);
        s1 = make_float4(f1.x+g1.x, f1.y+g1.y, f1.z+g1.z, f1.w+g1.w);
        s2 = make_float4(f2.x+g2.x, f2.y+g2.y, f2.z+g2.z, f2.w+g2.w);
        s3 = make_float4(f3.x+g3.x, f3.y+g3.y, f3.z+g3.z, f3.w+g3.w);
    }
    float4 hq = (q==0) ? s0 : (q==1) ? s1 : (q==2) ? s2 : s3;
    float4 xv = *(const float4*)(a.p[0] + (size_t)b*16 + tq);
    int4   mv = *(const int4*)(masks + (size_t)b*16 + tq);
    float impv[4];
    impv[0] = mv.x ? xv.x : hq.x;
    impv[1] = mv.y ? xv.y : hq.y;
    impv[2] = mv.z ? xv.z : hq.z;
    impv[3] = mv.w ? xv.w : hq.w;
    float latv[4];
    #pragma unroll
    for (int j = 0; j < 4; j++) {
        int t = tq + j;
        const float4* wr = (const float4*)(fw + t*16);
        float4 w0=wr[0], w1=wr[1], w2=wr[2], w3=wr[3];
        float l = fb[t];
        l += s0.x*w0.x + s0.y*w0.y + s0.z*w0.z + s0.w*w0.w;
        l += s1.x*w1.x + s1.y*w1.y + s1.z*w1.z + s1.w*w1.w;
        l += s2.x*w2.x + s2.y*w2.y + s2.z*w2.z + s2.w*w2.w;
        l += s3.x*w3.x + s3.y*w3.y + s3.z*w3.z + s3.w*w3.w;
        latv[j] = l;
    }
    float dv[4];
    #pragma unroll
    for (int j = 0; j < 4; j++) {
        float xx = fminf(fmaxf(impv[j], -8.f), 8.f);
        float f = (xx + 8.f) * 128.f;
        float fi = floorf(f);
        int i = (int)fi; i = i > NTAB-2 ? NTAB-2 : i;
        float w = f - fi;
        dv[j] = fmaf(w, tab[i+1] - tab[i], tab[i]);
    }
    float4 rv = ((const float4*)rec)[q];
    size_t eo = (size_t)b*16 + tq;
    *(float4*)(out + eo)        = make_float4(impv[0], impv[1], impv[2], impv[3]);
    *(float4*)(out + BS + eo)   = make_float4(dv[0], dv[1], dv[2], dv[3]);
    *(float4*)(out + 2*BS + eo) = make_float4(latv[0], latv[1], latv[2], latv[3]);
    *(float4*)(out + 3*BS + eo) = rv;
}

extern "C" void kernel_launch(void* const* d_in, const int* in_sizes, int n_in,
                              void* d_out, int out_size, void* d_ws, size_t ws_size,
                              hipStream_t stream)
{
    float* ws = (float*)d_ws;
    P29 a;
    for (int i = 0; i < 29; i++) a.p[i] = (const float*)d_in[i];
    const int* masks = (const int*)d_in[1];
    k_main<<<NSCAN + NTABB + 1, 256, 0, stream>>>(a, masks, ws);  // scan ∥ table ∥ decoder
    k_post<<<(BB*4)/256, 256, 0, stream>>>(a, masks, ws, (float*)d_out);
}